// Round 8
// baseline (351.199 us; speedup 1.0000x reference)
//
#include <hip/hip_runtime.h>
#include <hip/hip_fp16.h>
#include <math.h>

#define NN 40000
#define EE 640000
#define EP 680000   // EE + NN (self loops)
#define FIN0 32
#define HC 128      // H*C
#define GG 1000
#define MM 256
#define SCAN_BLOCKS ((NN + 255) / 256)   // 157
#define PROJ_BLOCKS ((NN + 127) / 128)   // 313

// ---------------- CSR construction ----------------

__global__ void hist_kernel(const int* __restrict__ ei, int* __restrict__ deg,
                            int* __restrict__ rank) {
    int idx = blockIdx.x * 256 + threadIdx.x;
    if (idx >= EP) return;
    int d = (idx < EE) ? ei[EE + idx] : (idx - EE);
    rank[idx] = atomicAdd(&deg[d], 1);
}

// One-kernel exclusive scan: each block computes its cross-block base by
// grid-striding deg[0 .. b*256) (<=3.2M coalesced loads total — cheap), then
// a local 256-prefix ladder. Replaces the scan_partial/scan_top 2-kernel pair.

__global__ __launch_bounds__(256) void scan_kernel(const int* __restrict__ deg,
                                                   int* __restrict__ offs) {
    int b = blockIdx.x, t = threadIdx.x;
    int s = 0;
    for (int i = t; i < b * 256; i += 256) s += deg[i];
#pragma unroll
    for (int d = 1; d < 64; d <<= 1) s += __shfl_xor(s, d);
    __shared__ int wsum[4];
    if ((t & 63) == 0) wsum[t >> 6] = s;
    __syncthreads();
    int base = wsum[0] + wsum[1] + wsum[2] + wsum[3];

    int i = b * 256 + t;
    int v = (i < NN) ? deg[i] : 0;
    __shared__ int tmp[256];
    tmp[t] = v;
    __syncthreads();
    for (int st = 1; st < 256; st <<= 1) {
        int add = (t >= st) ? tmp[t - st] : 0;
        __syncthreads();
        tmp[t] += add;
        __syncthreads();
    }
    int excl = tmp[t] - v + base;
    if (i < NN) offs[i] = excl;
    if (i == NN - 1) offs[NN] = excl + v;
}

__global__ void scatter_kernel(const int* __restrict__ ei, const int* __restrict__ offs,
                               const int* __restrict__ rank, int* __restrict__ esrc) {
    int idx = blockIdx.x * 256 + threadIdx.x;
    if (idx >= EP) return;
    int s, d;
    if (idx < EE) { s = ei[idx]; d = ei[EE + idx]; } else { s = idx - EE; d = s; }
    esrc[offs[d] + rank[idx]] = s;
}

// ---------------- Projection GEMM + fused attention logits ----------------
// 128 nodes x 128 chans per block, 8x8 register micro-tile (was 64x128/4x8 —
// halves LDS-staging bytes and sync count per FLOP). H stored fp16; logits
// from the exact fp32 register tile.

template <int FIN>
__global__ __launch_bounds__(256) void proj_kernel(const float* __restrict__ X,
                                                   const float* __restrict__ W,
                                                   const float* __restrict__ a_src,
                                                   const float* __restrict__ a_dst,
                                                   __half* __restrict__ H2,
                                                   float* __restrict__ als,
                                                   float* __restrict__ ald) {
    constexpr int KT = 32;
    static_assert(FIN % KT == 0, "FIN % KT");
    __shared__ float xs[KT][132];   // [k][node 0..127], pad 132 (float4-aligned)
    __shared__ float ws[KT][128];   // [k][chan]
    int t = threadIdx.x;
    int node0 = blockIdx.x * 128;
    int nt = t & 15;   // node group: nodes 8*nt..8*nt+7
    int ct = t >> 4;   // chan group: chans 8*ct..8*ct+7
    float acc[8][8];
#pragma unroll
    for (int i = 0; i < 8; i++)
#pragma unroll
        for (int j = 0; j < 8; j++) acc[i][j] = 0.f;

    for (int kk = 0; kk < FIN; kk += KT) {
        // stage X chunk (128 nodes x KT), transposed; float4 along k
#pragma unroll
        for (int r = 0; r < 4; r++) {
            int idx = r * 256 + t;
            int n = idx >> 3;             // 0..127
            int k = (idx & 7) * 4;        // 0,4,..,28
            int gn = node0 + n;
            if (gn >= NN) gn = NN - 1;    // safe dummy
            float4 v = *(const float4*)(&X[(size_t)gn * FIN + kk + k]);
            xs[k + 0][n] = v.x;
            xs[k + 1][n] = v.y;
            xs[k + 2][n] = v.z;
            xs[k + 3][n] = v.w;
        }
        // stage W chunk (KT x 128), float4 along c
#pragma unroll
        for (int r = 0; r < 4; r++) {
            int idx = r * 256 + t;
            int k = idx >> 5;             // 0..31
            int c = (idx & 31) * 4;       // 0..124
            *(float4*)(&ws[k][c]) = *(const float4*)(&W[(size_t)(kk + k) * 128 + c]);
        }
        __syncthreads();
#pragma unroll
        for (int k = 0; k < KT; k++) {
            const float4 xa = *(const float4*)(&xs[k][8 * nt]);
            const float4 xb = *(const float4*)(&xs[k][8 * nt + 4]);
            const float4 wa = *(const float4*)(&ws[k][8 * ct]);
            const float4 wb = *(const float4*)(&ws[k][8 * ct + 4]);
            float xr[8] = {xa.x, xa.y, xa.z, xa.w, xb.x, xb.y, xb.z, xb.w};
            float wr[8] = {wa.x, wa.y, wa.z, wa.w, wb.x, wb.y, wb.z, wb.w};
#pragma unroll
            for (int i = 0; i < 8; i++)
#pragma unroll
                for (int j = 0; j < 8; j++) acc[i][j] = fmaf(xr[i], wr[j], acc[i][j]);
        }
        __syncthreads();
    }
#pragma unroll
    for (int i = 0; i < 8; i++) {
        int n = node0 + 8 * nt + i;
        if (n < NN) {
            __half2 p0 = __floats2half2_rn(acc[i][0], acc[i][1]);
            __half2 p1 = __floats2half2_rn(acc[i][2], acc[i][3]);
            __half2 p2 = __floats2half2_rn(acc[i][4], acc[i][5]);
            __half2 p3 = __floats2half2_rn(acc[i][6], acc[i][7]);
            uint4 pk;
            pk.x = *(unsigned*)&p0; pk.y = *(unsigned*)&p1;
            pk.z = *(unsigned*)&p2; pk.w = *(unsigned*)&p3;
            *(uint4*)(&H2[(size_t)n * HC + 8 * ct]) = pk;
        }
    }
    // fused attention logits: chans 8*ct..8*ct+7 are half of head ct>>1
    float sa[8], da[8];
#pragma unroll
    for (int i = 0; i < 8; i++) { sa[i] = 0.f; da[i] = 0.f; }
#pragma unroll
    for (int j = 0; j < 8; j++) {
        float av = a_src[ct * 8 + j];
        float dv = a_dst[ct * 8 + j];
#pragma unroll
        for (int i = 0; i < 8; i++) {
            sa[i] = fmaf(acc[i][j], av, sa[i]);
            da[i] = fmaf(acc[i][j], dv, da[i]);
        }
    }
#pragma unroll
    for (int i = 0; i < 8; i++) {
        sa[i] += __shfl_xor(sa[i], 16);   // partner lane: same nt, ct^1
        da[i] += __shfl_xor(da[i], 16);
    }
    if ((ct & 1) == 0) {
        int head = ct >> 1;
#pragma unroll
        for (int i = 0; i < 8; i++) {
            int n = node0 + 8 * nt + i;
            if (n < NN) {
                als[n * 8 + head] = sa[i];
                ald[n * 8 + head] = da[i];
            }
        }
    }
}

// ---------------- fused softmax + aggregation per dst node ----------------
// At the random-256B-gather HBM ceiling (~3.6 TB/s fetch-side; verified across
// fp32 and fp16 variants). 4 nodes/256-block, 16 lanes x float4 per row,
// 4 edge slots/wave, next-chunk esrc->als chain software-pipelined.

__global__ __launch_bounds__(256) void agg_kernel(const __half* __restrict__ H2,
                                                  const float* __restrict__ als,
                                                  const float* __restrict__ ald,
                                                  const int* __restrict__ offs,
                                                  const int* __restrict__ esrc,
                                                  const float* __restrict__ bias,
                                                  float* __restrict__ OUT) {
    int t = threadIdx.x;
    int n = blockIdx.x * 4 + (t >> 6);
    int t6 = t & 63;
    int c8 = t6 & 15;          // channel group: chans [8*c8, 8*c8+8)
    int slot = (t6 >> 4) & 3;  // 4 edge slots per wave
    int hd = c8 >> 1;
    int beg = offs[n], end = offs[n + 1];
    float ad = ald[n * 8 + hd];
    float acc[8] = {0.f, 0.f, 0.f, 0.f, 0.f, 0.f, 0.f, 0.f};
    float denom = 0.f;
    const float4* H4 = (const float4*)H2;   // 8 halves per float4

    int p = beg + slot;
    int s_cur = 0; float al_cur = 0.f;
    if (p < end) {
        s_cur = esrc[p];
        al_cur = als[s_cur * 8 + hd];
    }
#pragma unroll 2
    while (p < end) {
        int pn = p + 4;
        int s_nxt = 0;
        if (pn < end) s_nxt = esrc[pn];
        float x = al_cur + ad;
        x = (x > 0.f) ? x : 0.2f * x;
        float w = __expf(x);
        float4 r = H4[(size_t)s_cur * 16 + c8];
        float al_nxt = 0.f;
        if (pn < end) al_nxt = als[s_nxt * 8 + hd];
        __half2 h0 = *(__half2*)&r.x;
        __half2 h1 = *(__half2*)&r.y;
        __half2 h2 = *(__half2*)&r.z;
        __half2 h3 = *(__half2*)&r.w;
        float2 f0 = __half22float2(h0);
        float2 f1 = __half22float2(h1);
        float2 f2 = __half22float2(h2);
        float2 f3 = __half22float2(h3);
        acc[0] = fmaf(w, f0.x, acc[0]); acc[1] = fmaf(w, f0.y, acc[1]);
        acc[2] = fmaf(w, f1.x, acc[2]); acc[3] = fmaf(w, f1.y, acc[3]);
        acc[4] = fmaf(w, f2.x, acc[4]); acc[5] = fmaf(w, f2.y, acc[5]);
        acc[6] = fmaf(w, f3.x, acc[6]); acc[7] = fmaf(w, f3.y, acc[7]);
        denom += w;
        s_cur = s_nxt; al_cur = al_nxt;
        p = pn;
    }
#pragma unroll
    for (int j = 0; j < 8; j++) {
        acc[j] += __shfl_xor(acc[j], 16);
        acc[j] += __shfl_xor(acc[j], 32);
    }
    denom += __shfl_xor(denom, 16);
    denom += __shfl_xor(denom, 32);
    if (slot == 0 && t6 < 16) {
        float inv = 1.0f / denom;
        const float4 ba = ((const float4*)bias)[2 * c8];
        const float4 bb = ((const float4*)bias)[2 * c8 + 1];
        float4 o0, o1;
        o0.x = fmaxf(fmaf(acc[0], inv, ba.x), 0.f);
        o0.y = fmaxf(fmaf(acc[1], inv, ba.y), 0.f);
        o0.z = fmaxf(fmaf(acc[2], inv, ba.z), 0.f);
        o0.w = fmaxf(fmaf(acc[3], inv, ba.w), 0.f);
        o1.x = fmaxf(fmaf(acc[4], inv, bb.x), 0.f);
        o1.y = fmaxf(fmaf(acc[5], inv, bb.y), 0.f);
        o1.z = fmaxf(fmaf(acc[6], inv, bb.z), 0.f);
        o1.w = fmaxf(fmaf(acc[7], inv, bb.w), 0.f);
        ((float4*)OUT)[(size_t)n * 32 + 2 * c8]     = o0;
        ((float4*)OUT)[(size_t)n * 32 + 2 * c8 + 1] = o1;
    }
}

// ---------------- fused mean-pool + MLP + head (2 graphs/block, 500 blocks) ----------------

__global__ __launch_bounds__(256) void mlp_fused(const float* __restrict__ B,
                                                 const int* __restrict__ batch,
                                                 const float* __restrict__ fW0,
                                                 const float* __restrict__ fb0,
                                                 const float* __restrict__ fW1,
                                                 const float* __restrict__ fb1,
                                                 const float* __restrict__ oW,
                                                 const float* __restrict__ ob,
                                                 float* __restrict__ out) {
    __shared__ int lo[3];
    __shared__ float rows[2][128];
    __shared__ float g1s[2][256];
    __shared__ float g2s[2][256];
    int t = threadIdx.x;
    int g0 = blockIdx.x * 2;
    if (t < 3) {
        int target = g0 + t;
        int a = 0, b = NN;
        while (a < b) { int mid = (a + b) >> 1; if (batch[mid] < target) a = mid + 1; else b = mid; }
        lo[t] = a;
    }
    __syncthreads();
    {
        int j = t >> 7, c = t & 127;
        int s0 = lo[j], s1 = lo[j + 1];
        float s = 0.f;
        float p0 = 0.f, p1 = 0.f, p2 = 0.f, p3 = 0.f;
        int n = s0;
        for (; n + 3 < s1; n += 4) {
            p0 += B[(size_t)n * 128 + c];
            p1 += B[(size_t)(n + 1) * 128 + c];
            p2 += B[(size_t)(n + 2) * 128 + c];
            p3 += B[(size_t)(n + 3) * 128 + c];
        }
        for (; n < s1; n++) s += B[(size_t)n * 128 + c];
        s += (p0 + p1) + (p2 + p3);
        rows[j][c] = s / fmaxf((float)(s1 - s0), 1.0f);
    }
    __syncthreads();
    float a0 = 0.f, a1 = 0.f;
#pragma unroll 8
    for (int k = 0; k < 128; k++) {
        float w = fW0[k * 256 + t];
        a0 = fmaf(rows[0][k], w, a0);
        a1 = fmaf(rows[1][k], w, a1);
    }
    float b0v = fb0[t];
    g1s[0][t] = fmaxf(a0 + b0v, 0.f);
    g1s[1][t] = fmaxf(a1 + b0v, 0.f);
    __syncthreads();
    a0 = 0.f; a1 = 0.f;
#pragma unroll 8
    for (int k = 0; k < 256; k++) {
        float w = fW1[k * 256 + t];
        a0 = fmaf(g1s[0][k], w, a0);
        a1 = fmaf(g1s[1][k], w, a1);
    }
    float b1v = fb1[t];
    g2s[0][t] = fmaxf(a0 + b1v, 0.f);
    g2s[1][t] = fmaxf(a1 + b1v, 0.f);
    __syncthreads();
    if (t < 64) {
        int jj = t >> 5, l = t & 31;
        float p0 = 0.f, p1 = 0.f;
#pragma unroll
        for (int k = l; k < 256; k += 32) {
            float v = g2s[jj][k];
            p0 = fmaf(v, oW[k * 2 + 0], p0);
            p1 = fmaf(v, oW[k * 2 + 1], p1);
        }
#pragma unroll
        for (int d = 1; d < 32; d <<= 1) {
            p0 += __shfl_xor(p0, d);
            p1 += __shfl_xor(p1, d);
        }
        if (l == 0) {
            out[(g0 + jj) * 2 + 0] = p0 + ob[0];
            out[(g0 + jj) * 2 + 1] = p1 + ob[1];
        }
    }
}

// ---------------- launch ----------------

extern "C" void kernel_launch(void* const* d_in, const int* in_sizes, int n_in,
                              void* d_out, int out_size, void* d_ws, size_t ws_size,
                              hipStream_t stream) {
    const float* x    = (const float*)d_in[0];
    const int* ei     = (const int*)d_in[1];
    const int* batch  = (const int*)d_in[2];
    const float* W[3]   = {(const float*)d_in[3], (const float*)d_in[7],  (const float*)d_in[11]};
    const float* bs[3]  = {(const float*)d_in[4], (const float*)d_in[8],  (const float*)d_in[12]};
    const float* asr[3] = {(const float*)d_in[5], (const float*)d_in[9],  (const float*)d_in[13]};
    const float* adt[3] = {(const float*)d_in[6], (const float*)d_in[10], (const float*)d_in[14]};
    const float* fW0 = (const float*)d_in[15];
    const float* fb0 = (const float*)d_in[16];
    const float* fW1 = (const float*)d_in[17];
    const float* fb1 = (const float*)d_in[18];
    const float* oW  = (const float*)d_in[19];
    const float* ob  = (const float*)d_in[20];
    float* out = (float*)d_out;

    char* base = (char*)d_ws;
    size_t off = 0;
    auto alloc = [&](size_t bytes) -> void* {
        void* p = base + off;
        off += (bytes + 255) & ~(size_t)255;
        return p;
    };
    int* deg    = (int*)alloc((size_t)NN * 4);
    int* offs   = (int*)alloc((size_t)(NN + 1) * 4);
    int* rank   = (int*)alloc((size_t)EP * 4);
    int* esrc   = (int*)alloc((size_t)EP * 4);
    __half* H2  = (__half*)alloc((size_t)NN * HC * 2);
    float* B    = (float*)alloc((size_t)NN * HC * 4);
    float* als  = (float*)alloc((size_t)NN * 8 * 4);
    float* ald  = (float*)alloc((size_t)NN * 8 * 4);

    hipMemsetAsync(deg, 0, (size_t)NN * 4, stream);

    hist_kernel<<<(EP + 255) / 256, 256, 0, stream>>>(ei, deg, rank);
    scan_kernel<<<SCAN_BLOCKS, 256, 0, stream>>>(deg, offs);
    scatter_kernel<<<(EP + 255) / 256, 256, 0, stream>>>(ei, offs, rank, esrc);

    const float* cur = x;
    for (int l = 0; l < 3; l++) {
        if (l == 0) proj_kernel<FIN0><<<PROJ_BLOCKS, 256, 0, stream>>>(cur, W[l], asr[l], adt[l], H2, als, ald);
        else        proj_kernel<HC><<<PROJ_BLOCKS, 256, 0, stream>>>(cur, W[l], asr[l], adt[l], H2, als, ald);
        agg_kernel<<<NN / 4, 256, 0, stream>>>(H2, als, ald, offs, esrc, bs[l], B);
        cur = B;
    }
    mlp_fused<<<GG / 2, 256, 0, stream>>>(B, batch, fW0, fb0, fW1, fb1, oW, ob, out);
}

// Round 9
// 318.229 us; speedup vs baseline: 1.1036x; 1.1036x over previous
//
#include <hip/hip_runtime.h>
#include <hip/hip_fp16.h>
#include <math.h>

#define NN 40000
#define EE 640000
#define EP 680000   // EE + NN (self loops)
#define FIN0 32
#define HC 128      // H*C
#define GG 1000
#define MM 256
#define SCAN_BLOCKS ((NN + 255) / 256)   // 157

// ---------------- CSR construction ----------------

__global__ void hist_kernel(const int* __restrict__ ei, int* __restrict__ deg,
                            int* __restrict__ rank) {
    int idx = blockIdx.x * 256 + threadIdx.x;
    if (idx >= EP) return;
    int d = (idx < EE) ? ei[EE + idx] : (idx - EE);
    rank[idx] = atomicAdd(&deg[d], 1);
}

__global__ __launch_bounds__(256) void scan_partial(const int* __restrict__ deg,
                                                    int* __restrict__ part) {
    int b = blockIdx.x, t = threadIdx.x;
    int i = b * 256 + t;
    int v = (i < NN) ? deg[i] : 0;
#pragma unroll
    for (int d = 1; d < 64; d <<= 1) v += __shfl_xor(v, d);
    __shared__ int ws[4];
    if ((t & 63) == 0) ws[t >> 6] = v;
    __syncthreads();
    if (t == 0) part[b] = ws[0] + ws[1] + ws[2] + ws[3];
}

__global__ __launch_bounds__(256) void scan_final(const int* __restrict__ deg,
                                                  const int* __restrict__ part,
                                                  int* __restrict__ offs) {
    int b = blockIdx.x, t = threadIdx.x;
    __shared__ int sbase;
    if (t < 64) {
        int s = 0;
        for (int l = t; l < b; l += 64) s += part[l];
#pragma unroll
        for (int d = 1; d < 64; d <<= 1) s += __shfl_xor(s, d);
        if (t == 0) sbase = s;
    }
    int i = b * 256 + t;
    int v = (i < NN) ? deg[i] : 0;
    __shared__ int tmp[256];
    tmp[t] = v;
    __syncthreads();
    for (int st = 1; st < 256; st <<= 1) {
        int add = (t >= st) ? tmp[t - st] : 0;
        __syncthreads();
        tmp[t] += add;
        __syncthreads();
    }
    int excl = tmp[t] - v + sbase;
    if (i < NN) offs[i] = excl;
    if (i == NN - 1) offs[NN] = excl + v;
}

__global__ void scatter_kernel(const int* __restrict__ ei, const int* __restrict__ offs,
                               const int* __restrict__ rank, int* __restrict__ esrc) {
    int idx = blockIdx.x * 256 + threadIdx.x;
    if (idx >= EP) return;
    int s, d;
    if (idx < EE) { s = ei[idx]; d = ei[EE + idx]; } else { s = idx - EE; d = s; }
    esrc[offs[d] + rank[idx]] = s;
}

// ---------------- Projection GEMM + fused attention logits ----------------
// 64 nodes x 128 chans, 4x8 micro-tile. (128x128/8x8 tried R8: VGPR-pressure
// regression, reverted.) H stored fp16; logits from the exact fp32 tile.

template <int FIN>
__global__ __launch_bounds__(256) void proj_kernel(const float* __restrict__ X,
                                                   const float* __restrict__ W,
                                                   const float* __restrict__ a_src,
                                                   const float* __restrict__ a_dst,
                                                   __half* __restrict__ H2,
                                                   float* __restrict__ als,
                                                   float* __restrict__ ald) {
    constexpr int KT = 32;
    static_assert(FIN % KT == 0, "FIN % KT");
    __shared__ float xs[KT][68];
    __shared__ float ws[KT][128];
    int t = threadIdx.x;
    int node0 = blockIdx.x * 64;
    int nt = t & 15;
    int ct = t >> 4;
    float acc[4][8];
#pragma unroll
    for (int i = 0; i < 4; i++)
#pragma unroll
        for (int j = 0; j < 8; j++) acc[i][j] = 0.f;

    for (int kk = 0; kk < FIN; kk += KT) {
#pragma unroll
        for (int r = 0; r < (64 * KT) / 256; r++) {
            int idx = r * 256 + t;
            int n = idx / KT, k = idx % KT;
            xs[k][n] = X[(node0 + n) * FIN + kk + k];
        }
#pragma unroll
        for (int r = 0; r < (KT * 128) / 256; r++) {
            int idx = r * 256 + t;
            int k = idx >> 7, c = idx & 127;
            ws[k][c] = W[(kk + k) * 128 + c];
        }
        __syncthreads();
#pragma unroll
        for (int k = 0; k < KT; k++) {
            const float4 xv = *(const float4*)(&xs[k][4 * nt]);
            const float4 wa = *(const float4*)(&ws[k][8 * ct]);
            const float4 wb = *(const float4*)(&ws[k][8 * ct + 4]);
            float xr[4] = {xv.x, xv.y, xv.z, xv.w};
            float wr[8] = {wa.x, wa.y, wa.z, wa.w, wb.x, wb.y, wb.z, wb.w};
#pragma unroll
            for (int i = 0; i < 4; i++)
#pragma unroll
                for (int j = 0; j < 8; j++) acc[i][j] = fmaf(xr[i], wr[j], acc[i][j]);
        }
        __syncthreads();
    }
#pragma unroll
    for (int i = 0; i < 4; i++) {
        int n = node0 + 4 * nt + i;
        __half2 p0 = __floats2half2_rn(acc[i][0], acc[i][1]);
        __half2 p1 = __floats2half2_rn(acc[i][2], acc[i][3]);
        __half2 p2 = __floats2half2_rn(acc[i][4], acc[i][5]);
        __half2 p3 = __floats2half2_rn(acc[i][6], acc[i][7]);
        uint4 pk;
        pk.x = *(unsigned*)&p0; pk.y = *(unsigned*)&p1;
        pk.z = *(unsigned*)&p2; pk.w = *(unsigned*)&p3;
        *(uint4*)(&H2[(size_t)n * HC + 8 * ct]) = pk;
    }
    float sa[4] = {0.f, 0.f, 0.f, 0.f}, da[4] = {0.f, 0.f, 0.f, 0.f};
#pragma unroll
    for (int j = 0; j < 8; j++) {
        float av = a_src[ct * 8 + j];
        float dv = a_dst[ct * 8 + j];
#pragma unroll
        for (int i = 0; i < 4; i++) {
            sa[i] = fmaf(acc[i][j], av, sa[i]);
            da[i] = fmaf(acc[i][j], dv, da[i]);
        }
    }
#pragma unroll
    for (int i = 0; i < 4; i++) {
        sa[i] += __shfl_xor(sa[i], 16);
        da[i] += __shfl_xor(da[i], 16);
    }
    if ((ct & 1) == 0) {
        int head = ct >> 1;
#pragma unroll
        for (int i = 0; i < 4; i++) {
            int n = node0 + 4 * nt + i;
            als[n * 8 + head] = sa[i];
            ald[n * 8 + head] = da[i];
        }
    }
}

// ---------------- fused softmax + aggregation per dst node ----------------
// At the random-256B-gather HBM ceiling (~3.6 TB/s fetch-side; verified across
// fp32 and fp16 variants). 4 nodes/256-block, 16 lanes x float4 per row,
// 4 edge slots/wave, next-chunk esrc->als chain software-pipelined.

__global__ __launch_bounds__(256) void agg_kernel(const __half* __restrict__ H2,
                                                  const float* __restrict__ als,
                                                  const float* __restrict__ ald,
                                                  const int* __restrict__ offs,
                                                  const int* __restrict__ esrc,
                                                  const float* __restrict__ bias,
                                                  float* __restrict__ OUT) {
    int t = threadIdx.x;
    int n = blockIdx.x * 4 + (t >> 6);
    int t6 = t & 63;
    int c8 = t6 & 15;          // channel group: chans [8*c8, 8*c8+8)
    int slot = (t6 >> 4) & 3;  // 4 edge slots per wave
    int hd = c8 >> 1;
    int beg = offs[n], end = offs[n + 1];
    float ad = ald[n * 8 + hd];
    float acc[8] = {0.f, 0.f, 0.f, 0.f, 0.f, 0.f, 0.f, 0.f};
    float denom = 0.f;
    const float4* H4 = (const float4*)H2;   // 8 halves per float4

    int p = beg + slot;
    int s_cur = 0; float al_cur = 0.f;
    if (p < end) {
        s_cur = esrc[p];
        al_cur = als[s_cur * 8 + hd];
    }
#pragma unroll 2
    while (p < end) {
        int pn = p + 4;
        int s_nxt = 0;
        if (pn < end) s_nxt = esrc[pn];
        float x = al_cur + ad;
        x = (x > 0.f) ? x : 0.2f * x;
        float w = __expf(x);
        float4 r = H4[(size_t)s_cur * 16 + c8];
        float al_nxt = 0.f;
        if (pn < end) al_nxt = als[s_nxt * 8 + hd];
        __half2 h0 = *(__half2*)&r.x;
        __half2 h1 = *(__half2*)&r.y;
        __half2 h2 = *(__half2*)&r.z;
        __half2 h3 = *(__half2*)&r.w;
        float2 f0 = __half22float2(h0);
        float2 f1 = __half22float2(h1);
        float2 f2 = __half22float2(h2);
        float2 f3 = __half22float2(h3);
        acc[0] = fmaf(w, f0.x, acc[0]); acc[1] = fmaf(w, f0.y, acc[1]);
        acc[2] = fmaf(w, f1.x, acc[2]); acc[3] = fmaf(w, f1.y, acc[3]);
        acc[4] = fmaf(w, f2.x, acc[4]); acc[5] = fmaf(w, f2.y, acc[5]);
        acc[6] = fmaf(w, f3.x, acc[6]); acc[7] = fmaf(w, f3.y, acc[7]);
        denom += w;
        s_cur = s_nxt; al_cur = al_nxt;
        p = pn;
    }
#pragma unroll
    for (int j = 0; j < 8; j++) {
        acc[j] += __shfl_xor(acc[j], 16);
        acc[j] += __shfl_xor(acc[j], 32);
    }
    denom += __shfl_xor(denom, 16);
    denom += __shfl_xor(denom, 32);
    if (slot == 0 && t6 < 16) {
        float inv = 1.0f / denom;
        const float4 ba = ((const float4*)bias)[2 * c8];
        const float4 bb = ((const float4*)bias)[2 * c8 + 1];
        float4 o0, o1;
        o0.x = fmaxf(fmaf(acc[0], inv, ba.x), 0.f);
        o0.y = fmaxf(fmaf(acc[1], inv, ba.y), 0.f);
        o0.z = fmaxf(fmaf(acc[2], inv, ba.z), 0.f);
        o0.w = fmaxf(fmaf(acc[3], inv, ba.w), 0.f);
        o1.x = fmaxf(fmaf(acc[4], inv, bb.x), 0.f);
        o1.y = fmaxf(fmaf(acc[5], inv, bb.y), 0.f);
        o1.z = fmaxf(fmaf(acc[6], inv, bb.z), 0.f);
        o1.w = fmaxf(fmaf(acc[7], inv, bb.w), 0.f);
        ((float4*)OUT)[(size_t)n * 32 + 2 * c8]     = o0;
        ((float4*)OUT)[(size_t)n * 32 + 2 * c8 + 1] = o1;
    }
}

// ---------------- fused mean-pool + MLP + head (2 graphs/block, 500 blocks) ----------------

__global__ __launch_bounds__(256) void mlp_fused(const float* __restrict__ B,
                                                 const int* __restrict__ batch,
                                                 const float* __restrict__ fW0,
                                                 const float* __restrict__ fb0,
                                                 const float* __restrict__ fW1,
                                                 const float* __restrict__ fb1,
                                                 const float* __restrict__ oW,
                                                 const float* __restrict__ ob,
                                                 float* __restrict__ out) {
    __shared__ int lo[3];
    __shared__ float rows[2][128];
    __shared__ float g1s[2][256];
    __shared__ float g2s[2][256];
    int t = threadIdx.x;
    int g0 = blockIdx.x * 2;
    if (t < 3) {
        int target = g0 + t;
        int a = 0, b = NN;
        while (a < b) { int mid = (a + b) >> 1; if (batch[mid] < target) a = mid + 1; else b = mid; }
        lo[t] = a;
    }
    __syncthreads();
    {
        int j = t >> 7, c = t & 127;
        int s0 = lo[j], s1 = lo[j + 1];
        float s = 0.f;
        float p0 = 0.f, p1 = 0.f, p2 = 0.f, p3 = 0.f;
        int n = s0;
        for (; n + 3 < s1; n += 4) {
            p0 += B[(size_t)n * 128 + c];
            p1 += B[(size_t)(n + 1) * 128 + c];
            p2 += B[(size_t)(n + 2) * 128 + c];
            p3 += B[(size_t)(n + 3) * 128 + c];
        }
        for (; n < s1; n++) s += B[(size_t)n * 128 + c];
        s += (p0 + p1) + (p2 + p3);
        rows[j][c] = s / fmaxf((float)(s1 - s0), 1.0f);
    }
    __syncthreads();
    float a0 = 0.f, a1 = 0.f;
#pragma unroll 8
    for (int k = 0; k < 128; k++) {
        float w = fW0[k * 256 + t];
        a0 = fmaf(rows[0][k], w, a0);
        a1 = fmaf(rows[1][k], w, a1);
    }
    float b0v = fb0[t];
    g1s[0][t] = fmaxf(a0 + b0v, 0.f);
    g1s[1][t] = fmaxf(a1 + b0v, 0.f);
    __syncthreads();
    a0 = 0.f; a1 = 0.f;
#pragma unroll 8
    for (int k = 0; k < 256; k++) {
        float w = fW1[k * 256 + t];
        a0 = fmaf(g1s[0][k], w, a0);
        a1 = fmaf(g1s[1][k], w, a1);
    }
    float b1v = fb1[t];
    g2s[0][t] = fmaxf(a0 + b1v, 0.f);
    g2s[1][t] = fmaxf(a1 + b1v, 0.f);
    __syncthreads();
    if (t < 64) {
        int jj = t >> 5, l = t & 31;
        float p0 = 0.f, p1 = 0.f;
#pragma unroll
        for (int k = l; k < 256; k += 32) {
            float v = g2s[jj][k];
            p0 = fmaf(v, oW[k * 2 + 0], p0);
            p1 = fmaf(v, oW[k * 2 + 1], p1);
        }
#pragma unroll
        for (int d = 1; d < 32; d <<= 1) {
            p0 += __shfl_xor(p0, d);
            p1 += __shfl_xor(p1, d);
        }
        if (l == 0) {
            out[(g0 + jj) * 2 + 0] = p0 + ob[0];
            out[(g0 + jj) * 2 + 1] = p1 + ob[1];
        }
    }
}

// ---------------- launch ----------------

extern "C" void kernel_launch(void* const* d_in, const int* in_sizes, int n_in,
                              void* d_out, int out_size, void* d_ws, size_t ws_size,
                              hipStream_t stream) {
    const float* x    = (const float*)d_in[0];
    const int* ei     = (const int*)d_in[1];
    const int* batch  = (const int*)d_in[2];
    const float* W[3]   = {(const float*)d_in[3], (const float*)d_in[7],  (const float*)d_in[11]};
    const float* bs[3]  = {(const float*)d_in[4], (const float*)d_in[8],  (const float*)d_in[12]};
    const float* asr[3] = {(const float*)d_in[5], (const float*)d_in[9],  (const float*)d_in[13]};
    const float* adt[3] = {(const float*)d_in[6], (const float*)d_in[10], (const float*)d_in[14]};
    const float* fW0 = (const float*)d_in[15];
    const float* fb0 = (const float*)d_in[16];
    const float* fW1 = (const float*)d_in[17];
    const float* fb1 = (const float*)d_in[18];
    const float* oW  = (const float*)d_in[19];
    const float* ob  = (const float*)d_in[20];
    float* out = (float*)d_out;

    char* base = (char*)d_ws;
    size_t off = 0;
    auto alloc = [&](size_t bytes) -> void* {
        void* p = base + off;
        off += (bytes + 255) & ~(size_t)255;
        return p;
    };
    int* deg    = (int*)alloc((size_t)NN * 4);
    int* offs   = (int*)alloc((size_t)(NN + 1) * 4);
    int* part   = (int*)alloc((size_t)SCAN_BLOCKS * 4);
    int* rank   = (int*)alloc((size_t)EP * 4);
    int* esrc   = (int*)alloc((size_t)EP * 4);
    __half* H2  = (__half*)alloc((size_t)NN * HC * 2);
    float* B    = (float*)alloc((size_t)NN * HC * 4);
    float* als  = (float*)alloc((size_t)NN * 8 * 4);
    float* ald  = (float*)alloc((size_t)NN * 8 * 4);

    hipMemsetAsync(deg, 0, (size_t)NN * 4, stream);

    hist_kernel<<<(EP + 255) / 256, 256, 0, stream>>>(ei, deg, rank);
    scan_partial<<<SCAN_BLOCKS, 256, 0, stream>>>(deg, part);
    scan_final<<<SCAN_BLOCKS, 256, 0, stream>>>(deg, part, offs);
    scatter_kernel<<<(EP + 255) / 256, 256, 0, stream>>>(ei, offs, rank, esrc);

    const float* cur = x;
    for (int l = 0; l < 3; l++) {
        if (l == 0) proj_kernel<FIN0><<<NN / 64, 256, 0, stream>>>(cur, W[l], asr[l], adt[l], H2, als, ald);
        else        proj_kernel<HC><<<NN / 64, 256, 0, stream>>>(cur, W[l], asr[l], adt[l], H2, als, ald);
        agg_kernel<<<NN / 4, 256, 0, stream>>>(H2, als, ald, offs, esrc, bs[l], B);
        cur = B;
    }
    mlp_fused<<<GG / 2, 256, 0, stream>>>(B, batch, fW0, fb0, fW1, fb1, oW, ob, out);
}